// Round 3
// baseline (141.431 us; speedup 1.0000x reference)
//
#include <hip/hip_runtime.h>

#define HSZ   16
#define TLEN  512
#define LOG2E 1.4426950408889634f

// ws layout (floats): [0..1023] scaled W_hh [64][16]; [1024..1087] scaled W_ih; [1088..1151] scaled (b_ih+b_hh)
__global__ __launch_bounds__(64) void prep_kernel(
    const float* __restrict__ W_ih, const float* __restrict__ W_hh,
    const float* __restrict__ b_ih, const float* __restrict__ b_hh,
    float* __restrict__ ws)
{
    const int r = threadIdx.x;  // 0..63 gate row, torch order i,f,g,o
    const float s = (r >= 32 && r < 48) ? (-2.0f * LOG2E) : (-LOG2E);  // tanh rows get -2*log2e
    #pragma unroll
    for (int k = 0; k < HSZ; ++k) ws[r * HSZ + k] = s * W_hh[r * HSZ + k];
    ws[1024 + r] = s * W_ih[r];
    ws[1088 + r] = s * (b_ih[r] + b_hh[r]);
}

// 32 lanes per batch element; lane l owns gate rows l (i|f: sigmoid) and 32+l (g: tanh | o: sigmoid).
// c_j and h_j live in lane 16+j. h broadcast via per-group LDS buffer (wave-synchronous, no barrier).
__global__ __launch_bounds__(64) void lstm_kernel(
    const float* __restrict__ x, const float* __restrict__ ws,
    const float* __restrict__ W_lin, float* __restrict__ out)
{
    __shared__ __align__(16) float xs[2 * TLEN];
    __shared__ __align__(16) float hbuf[2][HSZ];

    const int tid = threadIdx.x;
    const int g   = tid >> 5;   // batch group within wave (0,1)
    const int ll  = tid & 31;   // lane within group
    const int j   = ll & 15;    // hidden index

    // stage x for both batches (coalesced)
    const long xbase = (long)blockIdx.x * (2 * TLEN);
    #pragma unroll
    for (int i = 0; i < 2 * TLEN; i += 64) xs[i + tid] = x[xbase + i + tid];
    if (tid < 32) ((float*)hbuf)[tid] = 0.0f;
    __syncthreads();

    // per-lane weights (scaled): row rA = ll (sigmoid), row rB = 32+ll (tanh for ll<16, sigmoid for ll>=16)
    const int rA = ll;
    const int rB = 32 + ll;
    float4 wA[4], wB[4];
    #pragma unroll
    for (int q = 0; q < 4; ++q) {
        wA[q] = *(const float4*)(ws + rA * HSZ + 4 * q);
        wB[q] = *(const float4*)(ws + rB * HSZ + 4 * q);
    }
    const float wihA = ws[1024 + rA], wihB = ws[1024 + rB];
    const float bbA  = ws[1088 + rA], bbB  = ws[1088 + rB];
    const float mulB = (ll < 16) ? 2.0f : 1.0f;   // tanh = 2*sig(2x)-1
    const float addB = (ll < 16) ? -1.0f : 0.0f;

    const float* xg = xs + g * TLEN;
    float* hg = hbuf[g];

    float c = 0.0f, hnew = 0.0f;

    for (int t = 0; t < TLEN; ++t) {
        const float xt = xg[t];
        const float4 h0 = *(const float4*)(hg + 0);
        const float4 h1 = *(const float4*)(hg + 4);
        const float4 h2 = *(const float4*)(hg + 8);
        const float4 h3 = *(const float4*)(hg + 12);

        // gate pre-activations (already scaled so exp2(acc) gives e^{-x} / e^{-2x})
        float a0 = fmaf(xt, wihA, bbA);
        float b0 = fmaf(xt, wihB, bbB);
        float a1 = 0.0f, b1 = 0.0f;
        a0 = fmaf(h0.x, wA[0].x, a0);  a1 = fmaf(h0.y, wA[0].y, a1);
        a0 = fmaf(h0.z, wA[0].z, a0);  a1 = fmaf(h0.w, wA[0].w, a1);
        a0 = fmaf(h1.x, wA[1].x, a0);  a1 = fmaf(h1.y, wA[1].y, a1);
        a0 = fmaf(h1.z, wA[1].z, a0);  a1 = fmaf(h1.w, wA[1].w, a1);
        a0 = fmaf(h2.x, wA[2].x, a0);  a1 = fmaf(h2.y, wA[2].y, a1);
        a0 = fmaf(h2.z, wA[2].z, a0);  a1 = fmaf(h2.w, wA[2].w, a1);
        a0 = fmaf(h3.x, wA[3].x, a0);  a1 = fmaf(h3.y, wA[3].y, a1);
        a0 = fmaf(h3.z, wA[3].z, a0);  a1 = fmaf(h3.w, wA[3].w, a1);
        b0 = fmaf(h0.x, wB[0].x, b0);  b1 = fmaf(h0.y, wB[0].y, b1);
        b0 = fmaf(h0.z, wB[0].z, b0);  b1 = fmaf(h0.w, wB[0].w, b1);
        b0 = fmaf(h1.x, wB[1].x, b0);  b1 = fmaf(h1.y, wB[1].y, b1);
        b0 = fmaf(h1.z, wB[1].z, b0);  b1 = fmaf(h1.w, wB[1].w, b1);
        b0 = fmaf(h2.x, wB[2].x, b0);  b1 = fmaf(h2.y, wB[2].y, b1);
        b0 = fmaf(h2.z, wB[2].z, b0);  b1 = fmaf(h2.w, wB[2].w, b1);
        b0 = fmaf(h3.x, wB[3].x, b0);  b1 = fmaf(h3.y, wB[3].y, b1);
        b0 = fmaf(h3.z, wB[3].z, b0);  b1 = fmaf(h3.w, wB[3].w, b1);

        const float accA = a0 + a1;
        const float accB = b0 + b1;

        // sigmoid(pre) = rcp(1 + exp2(scaled)); tanh via mulB/addB
        const float eA   = __builtin_amdgcn_exp2f(accA);
        const float sA   = __builtin_amdgcn_rcpf(1.0f + eA);           // i (ll<16) | f (ll>=16)
        const float eB   = __builtin_amdgcn_exp2f(accB);
        const float sB   = __builtin_amdgcn_rcpf(1.0f + eB);
        const float actB = fmaf(mulB, sB, addB);                        // tanh(g) | o

        const float p     = sA * actB;                 // lanes<16: i*tanh(g)
        const float packA = (ll < 16) ? p : sA;
        const float v1    = __shfl_xor(packA, 16);     // lanes>=16 receive p_j

        c = fmaf(sA, c, v1);                           // lanes>=16: f*c + i*g  (lanes<16: garbage, unused)
        const float u  = __builtin_amdgcn_exp2f(c * (-2.0f * LOG2E));
        const float th = fmaf(2.0f, __builtin_amdgcn_rcpf(1.0f + u), -1.0f);  // tanh(c)
        hnew = actB * th;                              // lanes>=16: o * tanh(c)

        __builtin_amdgcn_wave_barrier();
        if (ll >= 16) hg[j] = hnew;                    // publish h for next step
        __builtin_amdgcn_wave_barrier();
    }

    // out[b] = sum_j h_j * W_lin[j]; valid h lives in lanes 16..31
    float v = hnew * W_lin[j];
    v += __shfl_xor(v, 1);
    v += __shfl_xor(v, 2);
    v += __shfl_xor(v, 4);
    v += __shfl_xor(v, 8);
    if (ll == 16) out[blockIdx.x * 2 + g] = v;
}

extern "C" void kernel_launch(void* const* d_in, const int* in_sizes, int n_in,
                              void* d_out, int out_size, void* d_ws, size_t ws_size,
                              hipStream_t stream) {
    const float* x     = (const float*)d_in[0];
    const float* W_ih  = (const float*)d_in[1];
    const float* W_hh  = (const float*)d_in[2];
    const float* b_ih  = (const float*)d_in[3];
    const float* b_hh  = (const float*)d_in[4];
    const float* W_lin = (const float*)d_in[5];
    float* out = (float*)d_out;
    float* ws  = (float*)d_ws;

    const int B = in_sizes[0] / TLEN;  // 4096

    hipLaunchKernelGGL(prep_kernel, dim3(1), dim3(64), 0, stream,
                       W_ih, W_hh, b_ih, b_hh, ws);
    hipLaunchKernelGGL(lstm_kernel, dim3(B / 2), dim3(64), 0, stream,
                       x, ws, W_lin, out);
}